// Round 2
// baseline (150.576 us; speedup 1.0000x reference)
//
#include <hip/hip_runtime.h>
#include <math.h>

#define DIM   16384
#define NOBS  8192
#define EPSN  1e-20f

__device__ __forceinline__ float softf(float v, float tau) {
    float a = fmaxf(fabsf(v) - tau, 0.0f);
    return copysignf(a, v);   // v==0 -> +0, matches sign(0)*x == 0
}

__device__ __forceinline__ float dot4(float4 a, float4 b) {
    return a.x * b.x + a.y * b.y + a.z * b.z + a.w * b.w;
}

// ---------------------------------------------------------------------------
// K1: fused  r = A@x_cur - b,  r_old = A@x_old - b,  grad_partial = A^T r
// Grid: 256 blocks x 1024 threads. Block bid owns rows [bid*32, bid*32+32).
// Thread t owns columns { k*4096 + 4t .. +3 : k in 0..3 }  (float4 idx k*1024+t)
// A is read from HBM exactly once (512 MB).
// ---------------------------------------------------------------------------
__global__ __launch_bounds__(1024) void k1_fused(
    const float* __restrict__ A, const float* __restrict__ xc,
    const float* __restrict__ xo, const float* __restrict__ b,
    float* __restrict__ ws_gp,   // [256][DIM] grad partials
    float* __restrict__ ws_sc)   // [256][2]   (sum r^2, sum r_old^2)
{
    const int t   = threadIdx.x;
    const int bid = blockIdx.x;
    __shared__ float red[40];

    const float4* xc4 = (const float4*)xc;
    const float4* xo4 = (const float4*)xo;

    float4 xcq[4], xoq[4], gpq[4];
#pragma unroll
    for (int k = 0; k < 4; ++k) {
        xcq[k] = xc4[k * 1024 + t];
        xoq[k] = xo4[k * 1024 + t];
        gpq[k] = make_float4(0.f, 0.f, 0.f, 0.f);
    }

    float sum_r2 = 0.f, sum_ro2 = 0.f;
    const int row0 = bid * 32;

    float4 acur[4], anxt[4];
    {
        const float4* Ar = (const float4*)(A + (size_t)row0 * DIM);
#pragma unroll
        for (int k = 0; k < 4; ++k) acur[k] = Ar[k * 1024 + t];
    }

    for (int r = 0; r < 32; ++r) {
        // prefetch next row (drained by the vmcnt(0) before the barrier below,
        // i.e. it completes while we'd be waiting anyway)
        if (r < 31) {
            const float4* An = (const float4*)(A + (size_t)(row0 + r + 1) * DIM);
#pragma unroll
            for (int k = 0; k < 4; ++k) anxt[k] = An[k * 1024 + t];
        }

        float dc = 0.f, dn = 0.f;
#pragma unroll
        for (int k = 0; k < 4; ++k) {
            dc += dot4(acur[k], xcq[k]);
            dn += dot4(acur[k], xoq[k]);
        }
        // wave reduce (64 lanes)
#pragma unroll
        for (int off = 32; off > 0; off >>= 1) {
            dc += __shfl_down(dc, off);
            dn += __shfl_down(dn, off);
        }
        if ((t & 63) == 0) {
            red[(t >> 6) * 2 + 0] = dc;
            red[(t >> 6) * 2 + 1] = dn;
        }
        __syncthreads();
        if (t == 0) {
            float sc = 0.f, so = 0.f;
#pragma unroll
            for (int w = 0; w < 16; ++w) { sc += red[2 * w]; so += red[2 * w + 1]; }
            float bv = b[row0 + r];
            float rc = sc - bv;
            float ro = so - bv;
            red[32] = rc;
            sum_r2  += rc * rc;
            sum_ro2 += ro * ro;
        }
        __syncthreads();
        float rc = red[32];
#pragma unroll
        for (int k = 0; k < 4; ++k) {
            gpq[k].x += acur[k].x * rc;
            gpq[k].y += acur[k].y * rc;
            gpq[k].z += acur[k].z * rc;
            gpq[k].w += acur[k].w * rc;
        }
        if (r < 31) {
#pragma unroll
            for (int k = 0; k < 4; ++k) acur[k] = anxt[k];
        }
    }

    float4* gp4 = (float4*)(ws_gp + (size_t)bid * DIM);
#pragma unroll
    for (int k = 0; k < 4; ++k) gp4[k * 1024 + t] = gpq[k];
    if (t == 0) {
        ws_sc[bid * 2 + 0] = sum_r2;
        ws_sc[bid * 2 + 1] = sum_ro2;
    }
}

// ---------------------------------------------------------------------------
// K2: grad[j] = sum_p ws_gp[p][j]; plus masked vector reductions.
// Grid: 128 blocks x 128 threads, thread owns column j = bid*128 + t.
// Emits per-block partials of: gz2, gnz2, dz2, dnz2, gdz, gdnz, sum|xc|, sum|xo|
// ---------------------------------------------------------------------------
__global__ __launch_bounds__(128) void k2_reduce(
    const float* __restrict__ ws_gp, const float* __restrict__ xc,
    const float* __restrict__ xo, float* __restrict__ grad,
    float* __restrict__ ws_red)   // [128][8]
{
    const int t = threadIdx.x;
    const int j = blockIdx.x * 128 + t;

    float g = 0.f;
#pragma unroll 8
    for (int p = 0; p < 256; ++p) g += ws_gp[(size_t)p * DIM + j];
    grad[j] = g;

    float xcv = xc[j], xov = xo[j];
    float z  = (xcv == 0.f) ? 1.f : 0.f;
    float nz = 1.f - z;
    float d  = xcv - xov;

    float vals[8];
    vals[0] = g * g * z;
    vals[1] = g * g * nz;
    vals[2] = d * d * z;
    vals[3] = d * d * nz;
    vals[4] = g * d * z;
    vals[5] = g * d * nz;
    vals[6] = fabsf(xcv);
    vals[7] = fabsf(xov);

    __shared__ float s[16];
#pragma unroll
    for (int k = 0; k < 8; ++k) {
#pragma unroll
        for (int off = 32; off > 0; off >>= 1) vals[k] += __shfl_down(vals[k], off);
    }
    if ((t & 63) == 0) {
#pragma unroll
        for (int k = 0; k < 8; ++k) s[(t >> 6) * 8 + k] = vals[k];
    }
    __syncthreads();
    if (t == 0) {
#pragma unroll
        for (int k = 0; k < 8; ++k) ws_red[blockIdx.x * 8 + k] = s[k] + s[8 + k];
    }
}

// ---------------------------------------------------------------------------
// K3: single block, 256 threads. Finishes all scalar reductions, computes the
// stop-vector norms, builds feats[12], runs the step MLP, writes alpha+scalars.
// ---------------------------------------------------------------------------
__device__ __forceinline__ float blockReduce256(float v, float* sh) {
    const int t = threadIdx.x;
#pragma unroll
    for (int off = 32; off > 0; off >>= 1) v += __shfl_down(v, off);
    __syncthreads();
    if ((t & 63) == 0) sh[t >> 6] = v;
    __syncthreads();
    return sh[0] + sh[1] + sh[2] + sh[3];
}

__global__ __launch_bounds__(256) void k3_scalars(
    const float* __restrict__ ws_sc,   // [256][2]
    const float* __restrict__ ws_red,  // [128][8]
    const float* __restrict__ grad,    // [DIM]
    const float* __restrict__ xc,
    const float* __restrict__ mu, const float* __restrict__ sm,
    const float* __restrict__ Ws1, const float* __restrict__ Ws2,
    const float* __restrict__ Ws3, const float* __restrict__ Ws4,
    float* __restrict__ ws_out)        // alpha[8], grad_norm, diff_norm, stop_norm
{
    const int t = threadIdx.x;
    __shared__ float sh[4];
    __shared__ float feats[12];
    __shared__ float ba[32], bb[32];
    __shared__ float snorms[3];

    float sum_r2  = blockReduce256(ws_sc[2 * t + 0], sh);
    float sum_ro2 = blockReduce256(ws_sc[2 * t + 1], sh);

    float red8[8];
#pragma unroll
    for (int k = 0; k < 8; ++k) {
        float v = (t < 128) ? ws_red[t * 8 + k] : 0.f;
        red8[k] = blockReduce256(v, sh);
    }
    const float gz2 = red8[0], gnz2 = red8[1], dz2 = red8[2], dnz2 = red8[3];
    const float gdz = red8[4], gdnz = red8[5], sxc = red8[6], sxo = red8[7];

    const float grad_norm = sqrtf(gz2 + gnz2);
    const float diff_norm = sqrtf(dz2 + dnz2);
    const float m = mu[0], L = sm[0];
    const float invL = 1.f / L;
    const float gg_sel = (grad_norm > EPSN) ? 1.f : grad_norm; // grad_norm*gradN == g*gg_sel

    // stop-vector masked norms
    float svz2 = 0.f, svnz2 = 0.f;
    for (int i = t; i < DIM; i += 256) {
        float g  = grad[i];
        float x  = xc[i];
        float pv = softf(x - g * gg_sel * invL, m * invL);
        float sv = x - pv;
        if (x == 0.f) svz2 += sv * sv; else svnz2 += sv * sv;
    }
    svz2  = blockReduce256(svz2, sh);
    svnz2 = blockReduce256(svnz2, sh);

    if (t == 0) {
        float stop_norm = sqrtf(svz2 + svnz2);
        float smooth = 0.5f * sum_r2, old_smooth = 0.5f * sum_ro2;
        float nonsm = m * sxc, old_nonsm = m * sxo;
        float loss = smooth + nonsm, old_loss = old_smooth + old_nonsm;

        float fg = (grad_norm > EPSN) ? 1.f / grad_norm : 1.f;
        float fd = (diff_norm > EPSN) ? 1.f / diff_norm : 1.f;
        float fs = (stop_norm > EPSN) ? 1.f / stop_norm : 1.f;

        feats[0]  = m;
        feats[1]  = log1pf(old_loss) - log1pf(loss);
        feats[2]  = log1pf(old_smooth) - log1pf(smooth);
        feats[3]  = log1pf(old_nonsm) - log1pf(nonsm);
        feats[4]  = log1pf(grad_norm * fg * sqrtf(gz2));
        feats[5]  = log1pf(grad_norm * fg * sqrtf(gnz2));
        feats[6]  = log1pf(diff_norm * fd * sqrtf(dz2));
        feats[7]  = log1pf(diff_norm * fd * sqrtf(dnz2));
        feats[8]  = log1pf(stop_norm * fs * sqrtf(svz2));
        feats[9]  = log1pf(stop_norm * fs * sqrtf(svnz2));
        feats[10] = gdz  * fg * fd;
        feats[11] = gdnz * fg * fd;
        snorms[0] = grad_norm; snorms[1] = diff_norm; snorms[2] = stop_norm;
    }
    __syncthreads();

    // step MLP: 12 -> 30 -> 20 -> 10 -> 8
    if (t < 30) {
        float s0 = 0.f;
#pragma unroll
        for (int j = 0; j < 12; ++j) s0 += Ws1[t * 12 + j] * feats[j];
        ba[t] = fmaxf(s0, 0.f);
    }
    __syncthreads();
    if (t < 20) {
        float s0 = 0.f;
#pragma unroll
        for (int j = 0; j < 30; ++j) s0 += Ws2[t * 30 + j] * ba[j];
        bb[t] = fmaxf(s0, 0.f);
    }
    __syncthreads();
    if (t < 10) {
        float s0 = 0.f;
#pragma unroll
        for (int j = 0; j < 20; ++j) s0 += Ws3[t * 20 + j] * bb[j];
        ba[t] = fmaxf(s0, 0.f);
    }
    __syncthreads();
    if (t < 8) {
        float s0 = 0.f;
#pragma unroll
        for (int j = 0; j < 10; ++j) s0 += Ws4[t * 10 + j] * ba[j];
        ws_out[t] = s0;
    }
    if (t == 0) {
        ws_out[8]  = snorms[0];
        ws_out[9]  = snorms[1];
        ws_out[10] = snorms[2];
    }
}

// ---------------------------------------------------------------------------
// K4: per-column channels -> conv MLP (8->20->20->20->2) -> final update.
// Grid: 64 blocks x 256 threads, one column per thread.
// ---------------------------------------------------------------------------
__global__ __launch_bounds__(256) void k4_update(
    const float* __restrict__ grad, const float* __restrict__ xc,
    const float* __restrict__ xo, const float* __restrict__ mu,
    const float* __restrict__ sm, const float* __restrict__ ws_out,
    const float* __restrict__ Wu1, const float* __restrict__ Wu2,
    const float* __restrict__ Wu3, const float* __restrict__ Wu4,
    float* __restrict__ out)
{
    __shared__ float w1[160], w2[400], w3[400], w4[40];
    const int t = threadIdx.x;
    for (int i = t; i < 160; i += 256) w1[i] = Wu1[i];
    for (int i = t; i < 400; i += 256) w2[i] = Wu2[i];
    for (int i = t; i < 400; i += 256) w3[i] = Wu3[i];
    if (t < 40) w4[t] = Wu4[t];
    __syncthreads();

    const int j = blockIdx.x * 256 + t;
    const float m = mu[0], L = sm[0];
    const float invL = 1.f / L;
    const float gn = ws_out[8], dn = ws_out[9], sn = ws_out[10];
    float a[8];
#pragma unroll
    for (int k = 0; k < 8; ++k) a[k] = ws_out[k];

    const float g  = grad[j];
    const float x  = xc[j];
    const float xv = xo[j];
    const float z  = (x == 0.f) ? 1.f : 0.f;
    const float nz = 1.f - z;

    const float fg = (gn > EPSN) ? 1.f / gn : 1.f;
    const float fd = (dn > EPSN) ? 1.f / dn : 1.f;
    const float fs = (sn > EPSN) ? 1.f / sn : 1.f;
    const float gg = (gn > EPSN) ? g : gn * g;   // grad_norm * normalized_grad

    const float pv = softf(x - gg * invL, m * invL);
    const float sv = x - pv;

    const float gN = g * fg;
    const float dN = (x - xv) * fd;
    const float sN = sv * fs;

    float ch[8];
    ch[0] = a[0] * gN * z;
    ch[1] = a[1] * gN * nz;
    ch[2] = a[2] * sN * z;
    ch[3] = a[3] * sN * nz;
    ch[4] = a[4] * dN * z;
    ch[5] = a[5] * dN * nz;
    ch[6] = a[6] * (gN * nz) * (dN * nz);
    ch[7] = a[7] * (gN * z) * (dN * z);

    float h1[20];
#pragma unroll
    for (int i = 0; i < 20; ++i) {
        float s0 = 0.f;
#pragma unroll
        for (int k = 0; k < 8; ++k) s0 += w1[i * 8 + k] * ch[k];
        h1[i] = fmaxf(s0, 0.f);
    }
    float h2[20];
#pragma unroll
    for (int i = 0; i < 20; ++i) {
        float s0 = 0.f;
#pragma unroll
        for (int k = 0; k < 20; ++k) s0 += w2[i * 20 + k] * h1[k];
        h2[i] = fmaxf(s0, 0.f);
    }
    float h3[20];
#pragma unroll
    for (int i = 0; i < 20; ++i) {
        float s0 = 0.f;
#pragma unroll
        for (int k = 0; k < 20; ++k) s0 += w3[i * 20 + k] * h2[k];
        h3[i] = fmaxf(s0, 0.f);
    }
    float d0 = 0.f, d1 = 0.f;
#pragma unroll
    for (int k = 0; k < 20; ++k) {
        d0 += w4[k] * h3[k];
        d1 += w4[20 + k] * h3[k];
    }

    const float dir1 = d0 * z;
    const float dir2 = d1 * nz;
    const float arg  = x + (dir1 - gg + dn * dir2) * invL;
    out[j] = softf(arg, m * invL);
}

// ---------------------------------------------------------------------------
extern "C" void kernel_launch(void* const* d_in, const int* in_sizes, int n_in,
                              void* d_out, int out_size, void* d_ws, size_t ws_size,
                              hipStream_t stream)
{
    const float* x_old = (const float*)d_in[0];
    const float* x_cur = (const float*)d_in[1];
    const float* A     = (const float*)d_in[2];
    const float* b     = (const float*)d_in[3];
    const float* mu    = (const float*)d_in[4];
    const float* sm    = (const float*)d_in[5];
    const float* Wu1   = (const float*)d_in[6];
    const float* Wu2   = (const float*)d_in[7];
    const float* Wu3   = (const float*)d_in[8];
    const float* Wu4   = (const float*)d_in[9];
    const float* Ws1   = (const float*)d_in[10];
    const float* Ws2   = (const float*)d_in[11];
    const float* Ws3   = (const float*)d_in[12];
    const float* Ws4   = (const float*)d_in[13];
    float* out = (float*)d_out;

    float* ws       = (float*)d_ws;
    float* ws_gp    = ws;                          // 256 * 16384
    float* ws_sc    = ws_gp  + (size_t)256 * DIM;  // 512
    float* ws_red   = ws_sc  + 512;                // 1024
    float* ws_grad  = ws_red + 1024;               // 16384
    float* ws_alpha = ws_grad + DIM;               // 16

    k1_fused <<<256, 1024, 0, stream>>>(A, x_cur, x_old, b, ws_gp, ws_sc);
    k2_reduce<<<128, 128, 0, stream>>>(ws_gp, x_cur, x_old, ws_grad, ws_red);
    k3_scalars<<<1, 256, 0, stream>>>(ws_sc, ws_red, ws_grad, x_cur, mu, sm,
                                      Ws1, Ws2, Ws3, Ws4, ws_alpha);
    k4_update<<<64, 256, 0, stream>>>(ws_grad, x_cur, x_old, mu, sm, ws_alpha,
                                      Wu1, Wu2, Wu3, Wu4, out);
}

// Round 3
// 134.410 us; speedup vs baseline: 1.1203x; 1.1203x over previous
//
#include <hip/hip_runtime.h>
#include <math.h>

#define DIM   16384
#define NOBS  8192
#define EPSN  1e-20f

__device__ __forceinline__ float softf(float v, float tau) {
    float a = fmaxf(fabsf(v) - tau, 0.0f);
    return copysignf(a, v);   // v==0 -> +0, matches sign(0)*x == 0
}

__device__ __forceinline__ float dot4(float4 a, float4 b) {
    return a.x * b.x + a.y * b.y + a.z * b.z + a.w * b.w;
}

__device__ __forceinline__ float sum16(const float* p) {
    const float4* q = (const float4*)p;
    float4 s0 = q[0], s1 = q[1], s2 = q[2], s3 = q[3];
    float a = (s0.x + s0.y) + (s0.z + s0.w);
    float b = (s1.x + s1.y) + (s1.z + s1.w);
    float c = (s2.x + s2.y) + (s2.z + s2.w);
    float d = (s3.x + s3.y) + (s3.z + s3.w);
    return (a + b) + (c + d);
}

// ---------------------------------------------------------------------------
// K1: fused  r = A@x_cur - b,  r_old = A@x_old - b,  grad_partial = A^T r
// 256 blocks x 1024 threads; block owns 32 rows; thread owns 16 columns.
// ONE barrier per row: wave partials -> LDS (parity double-buffered);
// post-barrier every thread sums 16 partials via 4 broadcast b128 reads.
// ---------------------------------------------------------------------------
__global__ __launch_bounds__(1024) void k1_fused(
    const float* __restrict__ A, const float* __restrict__ xc,
    const float* __restrict__ xo, const float* __restrict__ b,
    float* __restrict__ ws_gp,   // [256][DIM] grad partials
    float* __restrict__ ws_sc)   // [256][2]   (sum r^2, sum r_old^2)
{
    const int t   = threadIdx.x;
    const int bid = blockIdx.x;
    __shared__ __align__(16) float redc[2][16];
    __shared__ __align__(16) float redo[2][16];
    __shared__ float bsh[32];

    const int row0 = bid * 32;
    if (t < 32) bsh[t] = b[row0 + t];

    const float4* xc4 = (const float4*)xc;
    const float4* xo4 = (const float4*)xo;

    float4 xcq[4], xoq[4], gpq[4];
#pragma unroll
    for (int k = 0; k < 4; ++k) {
        xcq[k] = xc4[k * 1024 + t];
        xoq[k] = xo4[k * 1024 + t];
        gpq[k] = make_float4(0.f, 0.f, 0.f, 0.f);
    }

    const float4* Arow = (const float4*)(A + (size_t)row0 * DIM);
    float4 acur[4], anxt[4];
#pragma unroll
    for (int k = 0; k < 4; ++k) acur[k] = Arow[k * 1024 + t];
    Arow += DIM / 4;

    float sum_r2 = 0.f, sum_ro2 = 0.f;
    __syncthreads();   // bsh visible

    for (int r = 0; r < 32; ++r) {
        // prefetch next row; the barrier's vmcnt(0) drain IS the stream time
        if (r < 31) {
#pragma unroll
            for (int k = 0; k < 4; ++k) anxt[k] = Arow[k * 1024 + t];
            Arow += DIM / 4;
        }

        float dc = 0.f, dn = 0.f;
#pragma unroll
        for (int k = 0; k < 4; ++k) {
            dc += dot4(acur[k], xcq[k]);
            dn += dot4(acur[k], xoq[k]);
        }
#pragma unroll
        for (int off = 32; off > 0; off >>= 1) {
            dc += __shfl_down(dc, off);
            dn += __shfl_down(dn, off);
        }
        if ((t & 63) == 0) {
            redc[r & 1][t >> 6] = dc;
            redo[r & 1][t >> 6] = dn;
        }
        __syncthreads();

        // every thread: rc via 4 broadcast float4 LDS reads + tree add
        float rc = sum16(redc[r & 1]) - bsh[r];
        if (t == 0) sum_r2 += rc * rc;
        if (t == 1) {
            float ro = sum16(redo[r & 1]) - bsh[r];
            sum_ro2 += ro * ro;
        }
#pragma unroll
        for (int k = 0; k < 4; ++k) {
            gpq[k].x += acur[k].x * rc;
            gpq[k].y += acur[k].y * rc;
            gpq[k].z += acur[k].z * rc;
            gpq[k].w += acur[k].w * rc;
        }
        if (r < 31) {
#pragma unroll
            for (int k = 0; k < 4; ++k) acur[k] = anxt[k];
        }
    }

    float4* gp4 = (float4*)(ws_gp + (size_t)bid * DIM);
#pragma unroll
    for (int k = 0; k < 4; ++k) gp4[k * 1024 + t] = gpq[k];
    if (t == 0) ws_sc[bid * 2 + 0] = sum_r2;
    if (t == 1) ws_sc[bid * 2 + 1] = sum_ro2;
}

// ---------------------------------------------------------------------------
// K2a: first-stage partial reduction of grad partials.
// 256 blocks x 256 threads = 65536 threads (BW-bound, not latency-bound).
// Block = (slice s of 64 partials) x (chunk of 256 columns).
// ---------------------------------------------------------------------------
__global__ __launch_bounds__(256) void k2a(
    const float* __restrict__ ws_gp, float* __restrict__ ws_gp2)
{
    const int t     = threadIdx.x;
    const int chunk = blockIdx.x & 63;
    const int s     = blockIdx.x >> 6;
    const int j     = chunk * 256 + t;

    const float* base = ws_gp + (size_t)s * 64 * DIM + j;
    float acc[4] = {0.f, 0.f, 0.f, 0.f};
#pragma unroll
    for (int pp = 0; pp < 16; ++pp) {
#pragma unroll
        for (int q = 0; q < 4; ++q)
            acc[q] += base[(size_t)(pp * 4 + q) * DIM];
    }
    ws_gp2[s * DIM + j] = (acc[0] + acc[1]) + (acc[2] + acc[3]);
}

// ---------------------------------------------------------------------------
// K2b: finalize grad, compute ALL per-column stats (incl. stop-vector norms;
// grad_norm*(grad/grad_norm) == grad so no global scalar needed).
// 64 blocks x 256 threads. Emits 10 partials per block.
// ---------------------------------------------------------------------------
__global__ __launch_bounds__(256) void k2b(
    const float* __restrict__ ws_gp2, const float* __restrict__ xc,
    const float* __restrict__ xo, const float* __restrict__ mu,
    const float* __restrict__ sm,
    float* __restrict__ grad, float* __restrict__ ws_red)  // [64][10]
{
    const int t = threadIdx.x;
    const int j = blockIdx.x * 256 + t;

    float g = (ws_gp2[j] + ws_gp2[DIM + j]) + (ws_gp2[2 * DIM + j] + ws_gp2[3 * DIM + j]);
    grad[j] = g;

    const float x  = xc[j];
    const float xv = xo[j];
    const float z  = (x == 0.f) ? 1.f : 0.f;
    const float nz = 1.f - z;
    const float d  = x - xv;
    const float m = mu[0], L = sm[0];
    const float invL = 1.f / L;
    const float pv = softf(x - g * invL, m * invL);
    const float sv = x - pv;

    float vals[10];
    vals[0] = g * g * z;
    vals[1] = g * g * nz;
    vals[2] = d * d * z;
    vals[3] = d * d * nz;
    vals[4] = g * d * z;
    vals[5] = g * d * nz;
    vals[6] = fabsf(x);
    vals[7] = fabsf(xv);
    vals[8] = sv * sv * z;
    vals[9] = sv * sv * nz;

    __shared__ float s[40];
#pragma unroll
    for (int k = 0; k < 10; ++k) {
#pragma unroll
        for (int off = 32; off > 0; off >>= 1) vals[k] += __shfl_down(vals[k], off);
    }
    if ((t & 63) == 0) {
#pragma unroll
        for (int k = 0; k < 10; ++k) s[(t >> 6) * 10 + k] = vals[k];
    }
    __syncthreads();
    if (t < 10)
        ws_red[blockIdx.x * 10 + t] = (s[t] + s[10 + t]) + (s[20 + t] + s[30 + t]);
}

// ---------------------------------------------------------------------------
// K3: pure scalar work: finish reductions, feats[12], step MLP -> alpha.
// ---------------------------------------------------------------------------
__device__ __forceinline__ float blockReduce256(float v, float* sh) {
    const int t = threadIdx.x;
#pragma unroll
    for (int off = 32; off > 0; off >>= 1) v += __shfl_down(v, off);
    __syncthreads();
    if ((t & 63) == 0) sh[t >> 6] = v;
    __syncthreads();
    return sh[0] + sh[1] + sh[2] + sh[3];
}

__global__ __launch_bounds__(256) void k3_scalars(
    const float* __restrict__ ws_sc,   // [256][2]
    const float* __restrict__ ws_red,  // [64][10]
    const float* __restrict__ mu,
    const float* __restrict__ Ws1, const float* __restrict__ Ws2,
    const float* __restrict__ Ws3, const float* __restrict__ Ws4,
    float* __restrict__ ws_out)        // alpha[8], grad_norm, diff_norm, stop_norm
{
    const int t = threadIdx.x;
    __shared__ float sh[4];
    __shared__ float feats[12];
    __shared__ float ba[32], bb[32];
    __shared__ float snorms[3];

    float sum_r2  = blockReduce256(ws_sc[2 * t + 0], sh);
    float sum_ro2 = blockReduce256(ws_sc[2 * t + 1], sh);

    float red10[10];
#pragma unroll
    for (int k = 0; k < 10; ++k) {
        float v = (t < 64) ? ws_red[t * 10 + k] : 0.f;
        red10[k] = blockReduce256(v, sh);
    }
    const float gz2 = red10[0], gnz2 = red10[1], dz2 = red10[2], dnz2 = red10[3];
    const float gdz = red10[4], gdnz = red10[5], sxc = red10[6], sxo = red10[7];
    const float svz2 = red10[8], svnz2 = red10[9];

    if (t == 0) {
        const float grad_norm = sqrtf(gz2 + gnz2);
        const float diff_norm = sqrtf(dz2 + dnz2);
        const float stop_norm = sqrtf(svz2 + svnz2);
        const float m = mu[0];
        float smooth = 0.5f * sum_r2, old_smooth = 0.5f * sum_ro2;
        float nonsm = m * sxc, old_nonsm = m * sxo;
        float loss = smooth + nonsm, old_loss = old_smooth + old_nonsm;

        float fg = (grad_norm > EPSN) ? 1.f / grad_norm : 1.f;
        float fd = (diff_norm > EPSN) ? 1.f / diff_norm : 1.f;
        float fs = (stop_norm > EPSN) ? 1.f / stop_norm : 1.f;

        feats[0]  = m;
        feats[1]  = log1pf(old_loss) - log1pf(loss);
        feats[2]  = log1pf(old_smooth) - log1pf(smooth);
        feats[3]  = log1pf(old_nonsm) - log1pf(nonsm);
        feats[4]  = log1pf(grad_norm * fg * sqrtf(gz2));
        feats[5]  = log1pf(grad_norm * fg * sqrtf(gnz2));
        feats[6]  = log1pf(diff_norm * fd * sqrtf(dz2));
        feats[7]  = log1pf(diff_norm * fd * sqrtf(dnz2));
        feats[8]  = log1pf(stop_norm * fs * sqrtf(svz2));
        feats[9]  = log1pf(stop_norm * fs * sqrtf(svnz2));
        feats[10] = gdz  * fg * fd;
        feats[11] = gdnz * fg * fd;
        snorms[0] = grad_norm; snorms[1] = diff_norm; snorms[2] = stop_norm;
    }
    __syncthreads();

    // step MLP: 12 -> 30 -> 20 -> 10 -> 8
    if (t < 30) {
        float s0 = 0.f;
#pragma unroll
        for (int j = 0; j < 12; ++j) s0 += Ws1[t * 12 + j] * feats[j];
        ba[t] = fmaxf(s0, 0.f);
    }
    __syncthreads();
    if (t < 20) {
        float s0 = 0.f;
#pragma unroll
        for (int j = 0; j < 30; ++j) s0 += Ws2[t * 30 + j] * ba[j];
        bb[t] = fmaxf(s0, 0.f);
    }
    __syncthreads();
    if (t < 10) {
        float s0 = 0.f;
#pragma unroll
        for (int j = 0; j < 20; ++j) s0 += Ws3[t * 20 + j] * bb[j];
        ba[t] = fmaxf(s0, 0.f);
    }
    __syncthreads();
    if (t < 8) {
        float s0 = 0.f;
#pragma unroll
        for (int j = 0; j < 10; ++j) s0 += Ws4[t * 10 + j] * ba[j];
        ws_out[t] = s0;
    }
    if (t == 0) {
        ws_out[8]  = snorms[0];
        ws_out[9]  = snorms[1];
        ws_out[10] = snorms[2];
    }
}

// ---------------------------------------------------------------------------
// K4: per-column channels -> conv MLP (8->20->20->20->2) -> final update.
// ---------------------------------------------------------------------------
__global__ __launch_bounds__(256) void k4_update(
    const float* __restrict__ grad, const float* __restrict__ xc,
    const float* __restrict__ xo, const float* __restrict__ mu,
    const float* __restrict__ sm, const float* __restrict__ ws_out,
    const float* __restrict__ Wu1, const float* __restrict__ Wu2,
    const float* __restrict__ Wu3, const float* __restrict__ Wu4,
    float* __restrict__ out)
{
    __shared__ float w1[160], w2[400], w3[400], w4[40];
    const int t = threadIdx.x;
    for (int i = t; i < 160; i += 256) w1[i] = Wu1[i];
    for (int i = t; i < 400; i += 256) w2[i] = Wu2[i];
    for (int i = t; i < 400; i += 256) w3[i] = Wu3[i];
    if (t < 40) w4[t] = Wu4[t];
    __syncthreads();

    const int j = blockIdx.x * 256 + t;
    const float m = mu[0], L = sm[0];
    const float invL = 1.f / L;
    const float gn = ws_out[8], dn = ws_out[9], sn = ws_out[10];
    float a[8];
#pragma unroll
    for (int k = 0; k < 8; ++k) a[k] = ws_out[k];

    const float g  = grad[j];
    const float x  = xc[j];
    const float xv = xo[j];
    const float z  = (x == 0.f) ? 1.f : 0.f;
    const float nz = 1.f - z;

    const float fg = (gn > EPSN) ? 1.f / gn : 1.f;
    const float fd = (dn > EPSN) ? 1.f / dn : 1.f;
    const float fs = (sn > EPSN) ? 1.f / sn : 1.f;
    const float gg = (gn > EPSN) ? g : gn * g;   // grad_norm * normalized_grad

    const float pv = softf(x - gg * invL, m * invL);
    const float sv = x - pv;

    const float gN = g * fg;
    const float dN = (x - xv) * fd;
    const float sN = sv * fs;

    float ch[8];
    ch[0] = a[0] * gN * z;
    ch[1] = a[1] * gN * nz;
    ch[2] = a[2] * sN * z;
    ch[3] = a[3] * sN * nz;
    ch[4] = a[4] * dN * z;
    ch[5] = a[5] * dN * nz;
    ch[6] = a[6] * (gN * nz) * (dN * nz);
    ch[7] = a[7] * (gN * z) * (dN * z);

    float h1[20];
#pragma unroll
    for (int i = 0; i < 20; ++i) {
        float s0 = 0.f;
#pragma unroll
        for (int k = 0; k < 8; ++k) s0 += w1[i * 8 + k] * ch[k];
        h1[i] = fmaxf(s0, 0.f);
    }
    float h2[20];
#pragma unroll
    for (int i = 0; i < 20; ++i) {
        float s0 = 0.f;
#pragma unroll
        for (int k = 0; k < 20; ++k) s0 += w2[i * 20 + k] * h1[k];
        h2[i] = fmaxf(s0, 0.f);
    }
    float h3[20];
#pragma unroll
    for (int i = 0; i < 20; ++i) {
        float s0 = 0.f;
#pragma unroll
        for (int k = 0; k < 20; ++k) s0 += w3[i * 20 + k] * h2[k];
        h3[i] = fmaxf(s0, 0.f);
    }
    float d0 = 0.f, d1 = 0.f;
#pragma unroll
    for (int k = 0; k < 20; ++k) {
        d0 += w4[k] * h3[k];
        d1 += w4[20 + k] * h3[k];
    }

    const float dir1 = d0 * z;
    const float dir2 = d1 * nz;
    const float arg  = x + (dir1 - gg + dn * dir2) * invL;
    out[j] = softf(arg, m * invL);
}

// ---------------------------------------------------------------------------
extern "C" void kernel_launch(void* const* d_in, const int* in_sizes, int n_in,
                              void* d_out, int out_size, void* d_ws, size_t ws_size,
                              hipStream_t stream)
{
    const float* x_old = (const float*)d_in[0];
    const float* x_cur = (const float*)d_in[1];
    const float* A     = (const float*)d_in[2];
    const float* b     = (const float*)d_in[3];
    const float* mu    = (const float*)d_in[4];
    const float* sm    = (const float*)d_in[5];
    const float* Wu1   = (const float*)d_in[6];
    const float* Wu2   = (const float*)d_in[7];
    const float* Wu3   = (const float*)d_in[8];
    const float* Wu4   = (const float*)d_in[9];
    const float* Ws1   = (const float*)d_in[10];
    const float* Ws2   = (const float*)d_in[11];
    const float* Ws3   = (const float*)d_in[12];
    const float* Ws4   = (const float*)d_in[13];
    float* out = (float*)d_out;

    float* ws       = (float*)d_ws;
    float* ws_gp    = ws;                           // 256 * DIM
    float* ws_sc    = ws_gp  + (size_t)256 * DIM;   // 512
    float* ws_gp2   = ws_sc  + 512;                 // 4 * DIM
    float* ws_red   = ws_gp2 + 4 * DIM;             // 640
    float* ws_grad  = ws_red + 640;                 // DIM
    float* ws_alpha = ws_grad + DIM;                // 16

    k1_fused <<<256, 1024, 0, stream>>>(A, x_cur, x_old, b, ws_gp, ws_sc);
    k2a      <<<256, 256,  0, stream>>>(ws_gp, ws_gp2);
    k2b      <<<64,  256,  0, stream>>>(ws_gp2, x_cur, x_old, mu, sm, ws_grad, ws_red);
    k3_scalars<<<1,  256,  0, stream>>>(ws_sc, ws_red, mu, Ws1, Ws2, Ws3, Ws4, ws_alpha);
    k4_update<<<64,  256,  0, stream>>>(ws_grad, x_cur, x_old, mu, sm, ws_alpha,
                                        Wu1, Wu2, Wu3, Wu4, out);
}